// Round 1
// baseline (3472.712 us; speedup 1.0000x reference)
//
#include <hip/hip_runtime.h>
#include <hip/hip_bf16.h>
#include <cstdint>
#include <cstddef>

// Problem constants (B=2, C=64, G=8, K=9, H=W=192)
constexpr int B_  = 2;
constexpr int HH  = 192;
constexpr int WW  = 192;
constexpr int HW_ = HH * WW;

__device__ __forceinline__ float leaky(float v) { return fmaxf(v, 0.1f * v); }

// ---------------------------------------------------------------------------
// K0: transpose w_dcn (o, c, 3, 3) -> wT[k][c][o] so deform weight loads are
// lane-coalesced (lane index = o).
// ---------------------------------------------------------------------------
__global__ void transpose_wdcn(const float* __restrict__ w, float* __restrict__ wT) {
  int tid = blockIdx.x * blockDim.x + threadIdx.x;   // 9*64*64 = 36864
  if (tid >= 9 * 64 * 64) return;
  int o = tid % 64;
  int c = (tid / 64) % 64;
  int k = tid / (64 * 64);
  wT[tid] = w[(o * 64 + c) * 9 + k];
}

// ---------------------------------------------------------------------------
// Direct 3x3 conv, pad=1. One thread computes 4 consecutive-x outputs.
// CONCAT: input channels [0,CIN/2) from in0, [CIN/2,CIN) from in1.
// addsrc != nullptr: residual add (same shape as output) after activation.
// ---------------------------------------------------------------------------
template<int CIN, int COUT, bool LEAKY, bool CONCAT>
__global__ __launch_bounds__(256) void conv3x3_kernel(
    const float* __restrict__ in0,
    const float* __restrict__ in1,
    const float* __restrict__ w,      // (COUT, CIN, 3, 3)
    const float* __restrict__ bias,   // (COUT)
    const float* __restrict__ addsrc, // (B, COUT, H, W) or nullptr
    float* __restrict__ outp)         // (B, COUT, H, W)
{
  constexpr int NQ = WW / 4;  // 48 quads per row
  int tid = blockIdx.x * blockDim.x + threadIdx.x;
  int total = B_ * COUT * HH * NQ;
  if (tid >= total) return;
  int xq = tid % NQ;
  int y  = (tid / NQ) % HH;
  int co = (tid / (NQ * HH)) % COUT;
  int b  = tid / (NQ * HH * COUT);
  int x0 = xq * 4;

  float a0 = 0.f, a1 = 0.f, a2 = 0.f, a3 = 0.f;
  const float* wp = w + (size_t)co * CIN * 9;

  #pragma unroll 4
  for (int ci = 0; ci < CIN; ++ci) {
    const float* plane;
    if (CONCAT) {
      plane = (ci < CIN / 2)
                ? (in0 + ((size_t)(b * (CIN / 2) + ci)) * HW_)
                : (in1 + ((size_t)(b * (CIN / 2) + (ci - CIN / 2))) * HW_);
    } else {
      plane = in0 + ((size_t)(b * CIN + ci)) * HW_;
    }
    const float* wc = wp + ci * 9;
    #pragma unroll
    for (int ky = 0; ky < 3; ++ky) {
      int yy = y + ky - 1;
      if ((unsigned)yy < (unsigned)HH) {
        const float* row = plane + yy * WW;
        float4 m = *(const float4*)(row + x0);          // x0..x0+3 (16B aligned)
        float vl = (x0 > 0)      ? row[x0 - 1] : 0.f;
        float vr = (x0 + 4 < WW) ? row[x0 + 4] : 0.f;
        float w0 = wc[ky * 3 + 0], w1 = wc[ky * 3 + 1], w2 = wc[ky * 3 + 2];
        a0 += w0 * vl  + w1 * m.x + w2 * m.y;
        a1 += w0 * m.x + w1 * m.y + w2 * m.z;
        a2 += w0 * m.y + w1 * m.z + w2 * m.w;
        a3 += w0 * m.z + w1 * m.w + w2 * vr;
      }
    }
  }
  float bv = bias[co];
  a0 += bv; a1 += bv; a2 += bv; a3 += bv;
  if (LEAKY) { a0 = leaky(a0); a1 = leaky(a1); a2 = leaky(a2); a3 = leaky(a3); }
  size_t oidx = (((size_t)b * COUT + co) * HH + y) * WW + x0;
  if (addsrc) {
    float4 s = *(const float4*)(addsrc + oidx);
    a0 += s.x; a1 += s.y; a2 += s.z; a3 += s.w;
  }
  float4 r; r.x = a0; r.y = a1; r.z = a2; r.w = a3;
  *(float4*)(outp + oidx) = r;
}

// ---------------------------------------------------------------------------
// Fused deformable conv: per block (64 threads) one 16-pixel row tile.
// Loop (k, g): sample 8 channels x 16 pixels bilinearly into LDS, then each
// thread (= output channel o) accumulates 16 pixel outputs.
// ---------------------------------------------------------------------------
__global__ __launch_bounds__(64) void deform_kernel(
    const float* __restrict__ x,     // (B, 64, H, W) previous_features
    const float* __restrict__ off,   // (B, 144, H, W) offset field
    const float* __restrict__ wT,    // (9, 64, 64) = w_dcn transposed [k][c][o]
    const float* __restrict__ bias,  // (64)
    float* __restrict__ outp)        // (B, 64, H, W) aligned
{
  int bid = blockIdx.x;              // b*H*12 + y*12 + xt
  int xt = bid % 12;
  int y  = (bid / 12) % HH;
  int b  = bid / (12 * HH);
  int x0 = xt * 16;
  int t   = threadIdx.x;
  int pix = t & 15;
  int cg0 = t >> 4;                  // 0..3

  __shared__ float smp[8][16];
  __shared__ float accT[64][17];

  float acc[16];
  #pragma unroll
  for (int i = 0; i < 16; ++i) acc[i] = 0.f;

  for (int k = 0; k < 9; ++k) {
    int ky = k / 3, kx = k % 3;
    for (int g = 0; g < 8; ++g) {
      // ---- sampling phase: this thread computes pixel `pix` for cg0 and cg0+4
      const float* offp = off + (((size_t)b * 144 + g * 18 + k * 2) * HH + y) * WW + x0 + pix;
      float dy = offp[0];
      float dx = offp[HW_];
      float py = (float)(y - 1 + ky) + dy;
      float px = (float)(x0 + pix - 1 + kx) + dx;
      float fy0 = floorf(py), fx0 = floorf(px);
      float wy1 = py - fy0, wx1 = px - fx0;
      float wy0 = 1.f - wy1, wx0 = 1.f - wx1;
      float fy1 = fy0 + 1.f, fx1 = fx0 + 1.f;
      bool vy0 = (fy0 >= 0.f) && (fy0 <= (float)(HH - 1));
      bool vy1 = (fy1 >= 0.f) && (fy1 <= (float)(HH - 1));
      bool vx0 = (fx0 >= 0.f) && (fx0 <= (float)(WW - 1));
      bool vx1 = (fx1 >= 0.f) && (fx1 <= (float)(WW - 1));
      int iy0 = (int)fminf(fmaxf(fy0, 0.f), (float)(HH - 1));
      int iy1 = (int)fminf(fmaxf(fy1, 0.f), (float)(HH - 1));
      int ix0 = (int)fminf(fmaxf(fx0, 0.f), (float)(WW - 1));
      int ix1 = (int)fminf(fmaxf(fx1, 0.f), (float)(WW - 1));
      float c00 = wy0 * wx0 * ((vy0 && vx0) ? 1.f : 0.f);
      float c01 = wy0 * wx1 * ((vy0 && vx1) ? 1.f : 0.f);
      float c10 = wy1 * wx0 * ((vy1 && vx0) ? 1.f : 0.f);
      float c11 = wy1 * wx1 * ((vy1 && vx1) ? 1.f : 0.f);
      int o00 = iy0 * WW + ix0, o01 = iy0 * WW + ix1;
      int o10 = iy1 * WW + ix0, o11 = iy1 * WW + ix1;
      #pragma unroll
      for (int i = 0; i < 2; ++i) {
        int cg = cg0 + 4 * i;
        const float* xp = x + ((size_t)(b * 64) + g * 8 + cg) * HW_;
        smp[cg][pix] = xp[o00] * c00 + xp[o01] * c01 + xp[o10] * c10 + xp[o11] * c11;
      }
      __syncthreads();
      // ---- accumulate phase: thread t = output channel o
      const float* wp = wT + ((size_t)k * 64 + g * 8) * 64 + t;
      #pragma unroll
      for (int cg = 0; cg < 8; ++cg) {
        float wv = wp[cg * 64];
        #pragma unroll
        for (int p = 0; p < 16; p += 4) {
          float4 sv = *(const float4*)&smp[cg][p];
          acc[p + 0] += sv.x * wv;
          acc[p + 1] += sv.y * wv;
          acc[p + 2] += sv.z * wv;
          acc[p + 3] += sv.w * wv;
        }
      }
      __syncthreads();
    }
  }
  // ---- epilogue: transpose in LDS for coalesced-ish stores
  float bv = bias[t];
  #pragma unroll
  for (int p = 0; p < 16; ++p) accT[t][p] = acc[p] + bv;
  __syncthreads();
  #pragma unroll
  for (int rep = 0; rep < 16; ++rep) {
    int o = cg0 * 16 + rep;
    outp[(((size_t)b * 64 + o) * HH + y) * WW + x0 + pix] = accT[o][pix];
  }
}

// ---------------------------------------------------------------------------
extern "C" void kernel_launch(void* const* d_in, const int* in_sizes, int n_in,
                              void* d_out, int out_size, void* d_ws, size_t ws_size,
                              hipStream_t stream)
{
  const float* prev  = (const float*)d_in[0];
  const float* offin = (const float*)d_in[1];
  const float* w_off = (const float*)d_in[2];
  const float* b_off = (const float*)d_in[3];
  const float* w_dcn = (const float*)d_in[4];
  const float* b_dcn = (const float*)d_in[5];
  const float* w_r1  = (const float*)d_in[6];
  const float* b_r1  = (const float*)d_in[7];
  const float* w_r2  = (const float*)d_in[8];
  const float* b_r2  = (const float*)d_in[9];
  float* out = (float*)d_out;

  float* ws      = (float*)d_ws;
  float* off     = ws;                                    // B*144*HW = 10,616,832 f
  float* aligned = off     + (size_t)B_ * 144 * HW_;      // B*64*HW  =  4,718,592 f
  float* r1buf   = aligned + (size_t)B_ * 64 * HW_;       // B*64*HW  =  4,718,592 f
  float* wT      = r1buf   + (size_t)B_ * 64 * HW_;       // 36,864 f  (total ~80.4 MB)

  // K0: weight transpose for deform
  transpose_wdcn<<<144, 256, 0, stream>>>(w_dcn, wT);

  // K1: offset conv  (64 -> 144, no activation)
  {
    int total = B_ * 144 * HH * (WW / 4);                 // 2,654,208
    conv3x3_kernel<64, 144, false, false>
        <<<total / 256, 256, 0, stream>>>(offin, nullptr, w_off, b_off, nullptr, off);
  }

  // K2: deformable conv -> aligned
  deform_kernel<<<B_ * HH * 12, 64, 0, stream>>>(prev, off, wT, b_dcn, aligned);

  // K3: r1 = leaky(conv(concat(aligned, prev)))  (128 -> 64)
  {
    int total = B_ * 64 * HH * (WW / 4);                  // 1,179,648
    conv3x3_kernel<128, 64, true, true>
        <<<total / 256, 256, 0, stream>>>(aligned, prev, w_r1, b_r1, nullptr, r1buf);
  }

  // K4: out = aligned + leaky(conv(r1))  (64 -> 64)
  {
    int total = B_ * 64 * HH * (WW / 4);
    conv3x3_kernel<64, 64, true, false>
        <<<total / 256, 256, 0, stream>>>(r1buf, nullptr, w_r2, b_r2, aligned, out);
  }
}

// Round 2
// 402.464 us; speedup vs baseline: 8.6286x; 8.6286x over previous
//
#include <hip/hip_runtime.h>
#include <hip/hip_bf16.h>
#include <cstdint>
#include <cstddef>

constexpr int B_ = 2;
constexpr int HH = 192, WW = 192, HW_ = HH * WW;
constexpr int HP = 194, WP = 194;   // padded spatial dims (pad=1)

typedef short bf16x8 __attribute__((ext_vector_type(8)));
typedef short s16x4  __attribute__((ext_vector_type(4)));
typedef float f32x4  __attribute__((ext_vector_type(4)));

__device__ __forceinline__ float bf2f(unsigned short h) {
  union { unsigned u; float f; } v; v.u = (unsigned)h << 16; return v.f;
}
__device__ __forceinline__ unsigned short f2bf(float f) {
  union { float f; unsigned u; } v; v.f = f;
  unsigned u = v.u;
  u += 0x7fffu + ((u >> 16) & 1u);   // round-to-nearest-even
  return (unsigned short)(u >> 16);
}
__device__ __forceinline__ float leaky(float v) { return fmaxf(v, 0.1f * v); }

// ---------------------------------------------------------------------------
// NCHW f32 (2,64,192,192) -> NHWC bf16, optionally padded to 194x194 interior.
// Block: one (b,y) row x 16-x chunk. DSTC = dest channel stride (64 or 128).
// ---------------------------------------------------------------------------
template<int DSTC, bool PAD>
__global__ __launch_bounds__(256) void to_nhwc(const float* __restrict__ src,
                                               unsigned short* __restrict__ dst,
                                               int coff)
{
  __shared__ float tile[16][65];
  int t = threadIdx.x;
  int xc = blockIdx.x * 16;
  int y = blockIdx.y % HH, b = blockIdx.y / HH;
  #pragma unroll
  for (int cp = 0; cp < 4; ++cp) {
    int c = cp * 16 + (t >> 4);
    tile[t & 15][c] = src[((size_t)(b * 64 + c) * HH + y) * WW + xc + (t & 15)];
  }
  __syncthreads();
  int x = t >> 4, c4 = (t & 15) * 4;
  s16x4 s;
  #pragma unroll
  for (int j = 0; j < 4; ++j) s[j] = (short)f2bf(tile[x][c4 + j]);
  size_t pbase = PAD
      ? ((size_t)(b * HP + y + 1) * WP + xc + x + 1) * DSTC + coff + c4
      : ((size_t)(b * HH + y) * WW + xc + x) * DSTC + coff + c4;
  *(s16x4*)&dst[pbase] = s;
}

// ---------------------------------------------------------------------------
// Weight transform: (O, CI, 3, 3) f32 -> [o][k][ci] bf16 for all four weights.
// ---------------------------------------------------------------------------
__global__ __launch_bounds__(256) void wxform(
    const float* __restrict__ w_off, const float* __restrict__ w_dcn,
    const float* __restrict__ w_r1,  const float* __restrict__ w_r2,
    unsigned short* __restrict__ wOffB, unsigned short* __restrict__ wDcnB,
    unsigned short* __restrict__ wR1B,  unsigned short* __restrict__ wR2B)
{
  int tid = blockIdx.x * 256 + threadIdx.x;   // 230400 total
  const float* src; unsigned short* dst; int CI, idx;
  if (tid < 82944)            { src = w_off; dst = wOffB; CI = 64;  idx = tid; }
  else if (tid < 119808)      { src = w_dcn; dst = wDcnB; CI = 64;  idx = tid - 82944; }
  else if (tid < 193536)      { src = w_r1;  dst = wR1B;  CI = 128; idx = tid - 119808; }
  else                        { src = w_r2;  dst = wR2B;  CI = 64;  idx = tid - 193536; }
  int ci = idx % CI;
  int k  = (idx / CI) % 9;
  int o  = idx / (CI * 9);
  dst[idx] = f2bf(src[((size_t)(o * CI) + ci) * 9 + k]);
}

// ---------------------------------------------------------------------------
// MFMA implicit-GEMM 3x3 conv. Input: padded NHWC bf16 [b][194][194][CIN].
// Weights: [co][k][ci] bf16 (k = ky*3+kx). Block = 256 thr = 4 waves, each
// wave owns 16 consecutive pixels of a 64-px row segment; NF co-fragments.
// OUTMODE 0: bf16 NCHW out     (K1 offset conv)
// OUTMODE 1: bf16 NHWC padded  (K3 -> r1_t)
// OUTMODE 2: f32 NCHW + bf16-NHWC residual (K4 final)
// ---------------------------------------------------------------------------
template<int CIN, int COUT, int NF, bool LEAKY_, int OUTMODE>
__global__ __launch_bounds__(256) void conv_mfma(
    const unsigned short* __restrict__ inT,
    const unsigned short* __restrict__ wB,
    const float* __restrict__ bias,
    const unsigned short* __restrict__ resid,
    void* __restrict__ outp)
{
  const int l  = threadIdx.x & 63;
  const int wv = threadIdx.x >> 6;
  const int lr = l & 15;          // frag row/col index
  const int lk = (l >> 4) * 8;    // frag k-offset
  const int y  = blockIdx.y % HH, b = blockIdx.y / HH;
  const int x0 = blockIdx.x * 64 + wv * 16;
  const int co0 = blockIdx.z * (NF * 16);
  constexpr int KTOT = 9 * CIN;

  f32x4 acc[NF];
  #pragma unroll
  for (int f = 0; f < NF; ++f) acc[f] = f32x4{0.f, 0.f, 0.f, 0.f};

  #pragma unroll
  for (int ky = 0; ky < 3; ++ky) {
    const unsigned short* rowp = inT + (size_t)((b * HP + y + ky) * WP) * CIN;
    #pragma unroll
    for (int kx = 0; kx < 3; ++kx) {
      const unsigned short* pb = rowp + (size_t)(x0 + kx + lr) * CIN + lk;
      const unsigned short* wb = wB + (size_t)(co0 + lr) * KTOT + (ky * 3 + kx) * CIN + lk;
      #pragma unroll
      for (int c = 0; c < CIN; c += 32) {
        bf16x8 pf = *(const bf16x8*)(pb + c);
        #pragma unroll
        for (int f = 0; f < NF; ++f) {
          bf16x8 wf = *(const bf16x8*)(wb + c + (size_t)f * 16 * KTOT);
          if (OUTMODE == 1)
            acc[f] = __builtin_amdgcn_mfma_f32_16x16x32_bf16(wf, pf, acc[f], 0, 0, 0);
          else
            acc[f] = __builtin_amdgcn_mfma_f32_16x16x32_bf16(pf, wf, acc[f], 0, 0, 0);
        }
      }
    }
  }

  if (OUTMODE == 0) {
    // C: row = pixel = (l>>4)*4+j, col = co = lr. bf16 NCHW store, 4x along x.
    int xs = x0 + (l >> 4) * 4;
    #pragma unroll
    for (int f = 0; f < NF; ++f) {
      int co = co0 + f * 16 + lr;
      float bv = bias[co];
      s16x4 s;
      #pragma unroll
      for (int j = 0; j < 4; ++j) {
        float v = acc[f][j] + bv;
        if (LEAKY_) v = leaky(v);
        s[j] = (short)f2bf(v);
      }
      *(s16x4*)((unsigned short*)outp + ((size_t)(b * COUT + co) * HH + y) * WW + xs) = s;
    }
  } else if (OUTMODE == 1) {
    // C: row = co = (l>>4)*4+j (+f*16), col = pixel = lr. NHWC padded store.
    int x = x0 + lr;
    #pragma unroll
    for (int f = 0; f < NF; ++f) {
      int co = f * 16 + (l >> 4) * 4;
      f32x4 bv = *(const f32x4*)&bias[co];
      s16x4 s;
      #pragma unroll
      for (int j = 0; j < 4; ++j) {
        float v = acc[f][j] + bv[j];
        if (LEAKY_) v = leaky(v);
        s[j] = (short)f2bf(v);
      }
      *(s16x4*)((unsigned short*)outp + ((size_t)(b * HP + y + 1) * WP + x + 1) * 64 + co) = s;
    }
  } else {
    // C: row = pixel, col = co. f32 NCHW store + residual from concat ch [0,64).
    int xs = x0 + (l >> 4) * 4;
    #pragma unroll
    for (int f = 0; f < NF; ++f) {
      int co = f * 16 + lr;
      float bv = bias[co];
      f32x4 o;
      #pragma unroll
      for (int j = 0; j < 4; ++j) {
        float v = acc[f][j] + bv;
        if (LEAKY_) v = leaky(v);
        int x = xs + j;
        v += bf2f(resid[((size_t)(b * HP + y + 1) * WP + x + 1) * 128 + co]);
        o[j] = v;
      }
      *(f32x4*)((float*)outp + ((size_t)(b * 64 + co) * HH + y) * WW + xs) = o;
    }
  }
}

// ---------------------------------------------------------------------------
// Deformable conv, MFMA version. Per block: 64-px row segment, loop 9 taps:
// sample 64px x 64ch bilinearly into LDS (bf16), then GEMM-accumulate.
// Output (aligned) written bf16 into concat_t channels [0,64).
// ---------------------------------------------------------------------------
__global__ __launch_bounds__(256) void deform_mfma(
    const unsigned short* __restrict__ xT,    // prev NHWC bf16 [b][192][192][64]
    const unsigned short* __restrict__ off,   // bf16 NCHW [b][144][192][192]
    const unsigned short* __restrict__ wB,    // [64][9*64] bf16
    const float* __restrict__ bias,
    unsigned short* __restrict__ concatT)     // [b][194][194][128]
{
  __shared__ __align__(16) unsigned short patch[64][72];   // +8 pad: 2-way banks
  const int t  = threadIdx.x;
  const int l  = t & 63;
  const int wv = t >> 6;
  const int lr = l & 15;
  const int lk = (l >> 4) * 8;
  const int y  = blockIdx.y % HH, b = blockIdx.y / HH;
  const int x0 = blockIdx.x * 64;
  const int pix = t & 63;       // sampling-phase pixel
  const int g0  = t >> 6;       // sampling-phase groups g0, g0+4

  f32x4 acc[4];
  #pragma unroll
  for (int f = 0; f < 4; ++f) acc[f] = f32x4{0.f, 0.f, 0.f, 0.f};

  const unsigned short* xb = xT + (size_t)b * HW_ * 64;

  for (int k = 0; k < 9; ++k) {
    int ky = k / 3, kx = k % 3;
    // ---- sampling phase: 2 groups per thread, 8 channels each (16B loads)
    #pragma unroll
    for (int gi = 0; gi < 2; ++gi) {
      int g = g0 + gi * 4;
      const unsigned short* offp =
          off + ((size_t)(b * 144 + g * 18 + k * 2) * HH + y) * WW + x0 + pix;
      float dy = bf2f(offp[0]);
      float dx = bf2f(offp[HW_]);
      float py = (float)(y - 1 + ky) + dy;
      float px = (float)(x0 + pix - 1 + kx) + dx;
      float fy0 = floorf(py), fx0 = floorf(px);
      float wy1 = py - fy0, wx1 = px - fx0;
      float wy0 = 1.f - wy1, wx0 = 1.f - wx1;
      float fy1 = fy0 + 1.f, fx1 = fx0 + 1.f;
      bool vy0 = (fy0 >= 0.f) && (fy0 <= (float)(HH - 1));
      bool vy1 = (fy1 >= 0.f) && (fy1 <= (float)(HH - 1));
      bool vx0 = (fx0 >= 0.f) && (fx0 <= (float)(WW - 1));
      bool vx1 = (fx1 >= 0.f) && (fx1 <= (float)(WW - 1));
      int iy0 = (int)fminf(fmaxf(fy0, 0.f), (float)(HH - 1));
      int iy1 = (int)fminf(fmaxf(fy1, 0.f), (float)(HH - 1));
      int ix0 = (int)fminf(fmaxf(fx0, 0.f), (float)(WW - 1));
      int ix1 = (int)fminf(fmaxf(fx1, 0.f), (float)(WW - 1));
      float c00 = wy0 * wx0 * ((vy0 && vx0) ? 1.f : 0.f);
      float c01 = wy0 * wx1 * ((vy0 && vx1) ? 1.f : 0.f);
      float c10 = wy1 * wx0 * ((vy1 && vx0) ? 1.f : 0.f);
      float c11 = wy1 * wx1 * ((vy1 && vx1) ? 1.f : 0.f);
      const unsigned short* xp = xb + g * 8;
      bf16x8 v00 = *(const bf16x8*)(xp + (size_t)(iy0 * WW + ix0) * 64);
      bf16x8 v01 = *(const bf16x8*)(xp + (size_t)(iy0 * WW + ix1) * 64);
      bf16x8 v10 = *(const bf16x8*)(xp + (size_t)(iy1 * WW + ix0) * 64);
      bf16x8 v11 = *(const bf16x8*)(xp + (size_t)(iy1 * WW + ix1) * 64);
      bf16x8 sv;
      #pragma unroll
      for (int j = 0; j < 8; ++j) {
        float s = bf2f((unsigned short)v00[j]) * c00
                + bf2f((unsigned short)v01[j]) * c01
                + bf2f((unsigned short)v10[j]) * c10
                + bf2f((unsigned short)v11[j]) * c11;
        sv[j] = (short)f2bf(s);
      }
      *(bf16x8*)&patch[pix][g * 8] = sv;
    }
    __syncthreads();
    // ---- GEMM phase: wave wv owns pixels [wv*16, wv*16+16)
    const unsigned short* wbase = wB + (size_t)lr * 576 + k * 64 + lk;
    #pragma unroll
    for (int c = 0; c < 64; c += 32) {
      bf16x8 pf = *(const bf16x8*)&patch[wv * 16 + lr][c + lk];
      #pragma unroll
      for (int f = 0; f < 4; ++f) {
        bf16x8 wf = *(const bf16x8*)(wbase + c + (size_t)f * 16 * 576);
        acc[f] = __builtin_amdgcn_mfma_f32_16x16x32_bf16(wf, pf, acc[f], 0, 0, 0);
      }
    }
    __syncthreads();
  }
  // ---- epilogue: NHWC bf16 store into concat channels [0,64)
  int x = x0 + wv * 16 + lr;
  #pragma unroll
  for (int f = 0; f < 4; ++f) {
    int co = f * 16 + (l >> 4) * 4;
    f32x4 bv = *(const f32x4*)&bias[co];
    s16x4 s;
    #pragma unroll
    for (int j = 0; j < 4; ++j) s[j] = (short)f2bf(acc[f][j] + bv[j]);
    *(s16x4*)&concatT[((size_t)(b * HP + y + 1) * WP + x + 1) * 128 + co] = s;
  }
}

// ---------------------------------------------------------------------------
extern "C" void kernel_launch(void* const* d_in, const int* in_sizes, int n_in,
                              void* d_out, int out_size, void* d_ws, size_t ws_size,
                              hipStream_t stream)
{
  const float* prev  = (const float*)d_in[0];
  const float* offin = (const float*)d_in[1];
  const float* w_off = (const float*)d_in[2];
  const float* b_off = (const float*)d_in[3];
  const float* w_dcn = (const float*)d_in[4];
  const float* b_dcn = (const float*)d_in[5];
  const float* w_r1  = (const float*)d_in[6];
  const float* b_r1  = (const float*)d_in[7];
  const float* w_r2  = (const float*)d_in[8];
  const float* b_r2  = (const float*)d_in[9];
  float* out = (float*)d_out;

  char* p = (char*)d_ws;
  unsigned short* offs_t   = (unsigned short*)p; p += (size_t)B_ * HP * WP * 64 * 2;   //  9.63 MB
  unsigned short* concat_t = (unsigned short*)p; p += (size_t)B_ * HP * WP * 128 * 2;  // 19.27 MB
  unsigned short* r1_t     = (unsigned short*)p; p += (size_t)B_ * HP * WP * 64 * 2;   //  9.63 MB
  unsigned short* prev_t   = (unsigned short*)p; p += (size_t)B_ * HW_ * 64 * 2;       //  9.44 MB
  unsigned short* offf     = (unsigned short*)p; p += (size_t)B_ * 144 * HW_ * 2;      // 21.23 MB
  unsigned short* wOffB    = (unsigned short*)p; p += 144 * 576 * 2;
  unsigned short* wDcnB    = (unsigned short*)p; p += 64 * 576 * 2;
  unsigned short* wR1B     = (unsigned short*)p; p += 64 * 1152 * 2;
  unsigned short* wR2B     = (unsigned short*)p; p += 64 * 576 * 2;                    // total ~69.7 MB

  // Zero the three padded NHWC buffers (contiguous) so pad borders are 0.
  hipMemsetAsync(offs_t, 0, (size_t)B_ * HP * WP * (64 + 128 + 64) * 2, stream);

  // Pre-pass: weight transforms + NHWC conversions.
  wxform<<<900, 256, 0, stream>>>(w_off, w_dcn, w_r1, w_r2, wOffB, wDcnB, wR1B, wR2B);
  to_nhwc<64,  true ><<<dim3(12, 384), 256, 0, stream>>>(offin, offs_t, 0);
  to_nhwc<128, true ><<<dim3(12, 384), 256, 0, stream>>>(prev,  concat_t, 64);
  to_nhwc<64,  false><<<dim3(12, 384), 256, 0, stream>>>(prev,  prev_t, 0);

  // K1: offset conv (64 -> 144), bf16 NCHW out.
  conv_mfma<64, 144, 3, false, 0><<<dim3(3, 384, 3), 256, 0, stream>>>(
      offs_t, wOffB, b_off, nullptr, offf);

  // K2: deformable conv -> concat_t channels [0,64).
  deform_mfma<<<dim3(3, 384), 256, 0, stream>>>(prev_t, offf, wDcnB, b_dcn, concat_t);

  // K3: r1 = leaky(conv(concat)) (128 -> 64), NHWC padded out.
  conv_mfma<128, 64, 4, true, 1><<<dim3(3, 384, 1), 256, 0, stream>>>(
      concat_t, wR1B, b_r1, nullptr, r1_t);

  // K4: out = aligned + leaky(conv(r1)) (64 -> 64), f32 NCHW out.
  conv_mfma<64, 64, 4, true, 2><<<dim3(3, 384, 1), 256, 0, stream>>>(
      r1_t, wR2B, b_r2, concat_t, out);
}

// Round 4
// 358.704 us; speedup vs baseline: 9.6813x; 1.1220x over previous
//
#include <hip/hip_runtime.h>
#include <hip/hip_bf16.h>
#include <cstdint>
#include <cstddef>

constexpr int B_ = 2;
constexpr int HH = 192, WW = 192, HW_ = HH * WW;
constexpr int HP = 194, WPAD = 200;   // padded dims; WPAD=200 so 72-px tiles never overrun

typedef short bf16x8 __attribute__((ext_vector_type(8)));
typedef short s16x4  __attribute__((ext_vector_type(4)));
typedef float f32x4  __attribute__((ext_vector_type(4)));

typedef __attribute__((address_space(1))) const void GLB;
typedef __attribute__((address_space(3))) void LDS;

__device__ __forceinline__ float bf2f(unsigned short h) {
  union { unsigned u; float f; } v; v.u = (unsigned)h << 16; return v.f;
}
__device__ __forceinline__ unsigned short f2bf(float f) {
  union { float f; unsigned u; } v; v.f = f;
  unsigned u = v.u;
  u += 0x7fffu + ((u >> 16) & 1u);
  return (unsigned short)(u >> 16);
}
__device__ __forceinline__ float leaky(float v) { return fmaxf(v, 0.1f * v); }

// ---------------------------------------------------------------------------
// NCHW f32 -> NHWC bf16 (optionally padded interior of [HP][WPAD]).
// ---------------------------------------------------------------------------
template<int DSTC, bool PAD>
__global__ __launch_bounds__(256) void to_nhwc(const float* __restrict__ src,
                                               unsigned short* __restrict__ dst,
                                               int coff)
{
  __shared__ float tile[16][65];
  int t = threadIdx.x;
  int xc = blockIdx.x * 16;
  int y = blockIdx.y % HH, b = blockIdx.y / HH;
  #pragma unroll
  for (int cp = 0; cp < 4; ++cp) {
    int c = cp * 16 + (t >> 4);
    tile[t & 15][c] = src[((size_t)(b * 64 + c) * HH + y) * WW + xc + (t & 15)];
  }
  __syncthreads();
  int x = t >> 4, c4 = (t & 15) * 4;
  s16x4 s;
  #pragma unroll
  for (int j = 0; j < 4; ++j) s[j] = (short)f2bf(tile[x][c4 + j]);
  size_t pbase = PAD
      ? ((size_t)(b * HP + y + 1) * WPAD + xc + x + 1) * DSTC + coff + c4
      : ((size_t)(b * HH + y) * WW + xc + x) * DSTC + coff + c4;
  *(s16x4*)&dst[pbase] = s;
}

// ---------------------------------------------------------------------------
// Weight transform: (O, CI, 3, 3) f32 -> [o][k][ci] bf16.
// ---------------------------------------------------------------------------
__global__ __launch_bounds__(256) void wxform(
    const float* __restrict__ w_off, const float* __restrict__ w_dcn,
    const float* __restrict__ w_r1,  const float* __restrict__ w_r2,
    unsigned short* __restrict__ wOffB, unsigned short* __restrict__ wDcnB,
    unsigned short* __restrict__ wR1B,  unsigned short* __restrict__ wR2B)
{
  int tid = blockIdx.x * 256 + threadIdx.x;   // 230400 total
  const float* src; unsigned short* dst; int CI, idx;
  if (tid < 82944)            { src = w_off; dst = wOffB; CI = 64;  idx = tid; }
  else if (tid < 119808)      { src = w_dcn; dst = wDcnB; CI = 64;  idx = tid - 82944; }
  else if (tid < 193536)      { src = w_r1;  dst = wR1B;  CI = 128; idx = tid - 119808; }
  else                        { src = w_r2;  dst = wR2B;  CI = 64;  idx = tid - 193536; }
  int ci = idx % CI;
  int k  = (idx / CI) % 9;
  int o  = idx / (CI * 9);
  dst[idx] = f2bf(src[((size_t)(o * CI) + ci) * 9 + k]);
}

// ---------------------------------------------------------------------------
// MFMA implicit-GEMM 3x3 conv with LDS row staging (stage -> barrier -> MFMA).
// Block = 256 thr (4 waves): 64-px row segment x all COUT.
// OUTMODE 0: bf16 NCHW out (K1) | 1: bf16 NHWC padded (K3) | 2: f32 NCHW + resid (K4)
// ---------------------------------------------------------------------------
template<int CIN, int COUT, int NF, bool LEAKY_, int OUTMODE>
__global__ __launch_bounds__(256) void conv_mfma(
    const unsigned short* __restrict__ inT,   // [b][HP][WPAD][CIN] bf16
    const unsigned short* __restrict__ wB,    // [COUT][9*CIN] bf16
    const float* __restrict__ bias,
    const unsigned short* __restrict__ resid,
    void* __restrict__ outp)
{
  constexpr int KTOT = 9 * CIN;
  constexpr int CPP  = CIN / 8;          // 16B chunks per pixel
  constexpr int TPX  = 72;
  constexpr int NCH  = TPX * CPP;        // chunks per staged row
  constexpr int RPR  = NCH / 64;         // wave-regions per row
  constexpr int NREG = 3 * RPR;
  __shared__ __align__(16) unsigned short tile[3 * TPX * CIN];

  const int t = threadIdx.x;
  const int l = t & 63, wv = t >> 6;
  const int lr = l & 15, lq = l >> 4, lk = lq * 8;

  // XCD-aware bijective swizzle (1152 % 8 == 0)
  constexpr int NWG = 3 * 384;
  int lin = blockIdx.x + 3 * blockIdx.y;
  int swz = (lin & 7) * (NWG / 8) + (lin >> 3);
  int xq = swz % 3, yy = swz / 3;
  int y = yy % HH, b = yy / HH;
  int x0 = xq * 64;

  // ---- stage 3 rows x 72 px (padded coords rows y..y+2, cols x0..x0+71)
  {
    const unsigned short* base = inT + ((size_t)(b * HP + y) * WPAD + x0) * CIN;
    for (int r = wv; r < NREG; r += 4) {
      int row = r / RPR;
      int rr  = r % RPR;
      int d   = rr * 64 + l;                  // dest chunk within row
      int p   = d / CPP;
      int cj  = d % CPP;
      int sc  = p * CPP + (cj ^ (p & (CPP - 1)));   // inverse-swizzled source
      const unsigned short* src = base + (size_t)row * WPAD * CIN + (size_t)sc * 8;
      unsigned short* dst = &tile[(size_t)(row * NCH + rr * 64) * 8];
      __builtin_amdgcn_global_load_lds((GLB*)src, (LDS*)dst, 16, 0, 0);
    }
  }
  __syncthreads();

  f32x4 acc[NF];
  #pragma unroll
  for (int f = 0; f < NF; ++f) acc[f] = f32x4{0.f, 0.f, 0.f, 0.f};

  #pragma unroll
  for (int ky = 0; ky < 3; ++ky) {
    #pragma unroll
    for (int kx = 0; kx < 3; ++kx) {
      const int px = wv * 16 + lr + kx;
      const unsigned short* wtap = wB + (ky * 3 + kx) * CIN + lk;
      #pragma unroll
      for (int c = 0; c < CIN; c += 32) {
        int cj = (c + lk) >> 3;
        bf16x8 pf = *(const bf16x8*)
            &tile[(size_t)(ky * NCH + px * CPP + (cj ^ (px & (CPP - 1)))) * 8];
        #pragma unroll
        for (int f = 0; f < NF; ++f) {
          bf16x8 wf = *(const bf16x8*)&wtap[(size_t)(f * 16 + lr) * KTOT + c];
          if (OUTMODE == 1)
            acc[f] = __builtin_amdgcn_mfma_f32_16x16x32_bf16(wf, pf, acc[f], 0, 0, 0);
          else
            acc[f] = __builtin_amdgcn_mfma_f32_16x16x32_bf16(pf, wf, acc[f], 0, 0, 0);
        }
      }
    }
  }

  if (OUTMODE == 0) {
    int xs = x0 + wv * 16 + lq * 4;
    #pragma unroll
    for (int f = 0; f < NF; ++f) {
      int co = f * 16 + lr;
      float bv = bias[co];
      s16x4 s;
      #pragma unroll
      for (int j = 0; j < 4; ++j) {
        float v = acc[f][j] + bv;
        if (LEAKY_) v = leaky(v);
        s[j] = (short)f2bf(v);
      }
      *(s16x4*)((unsigned short*)outp + ((size_t)(b * COUT + co) * HH + y) * WW + xs) = s;
    }
  } else if (OUTMODE == 1) {
    int x = x0 + wv * 16 + lr;
    #pragma unroll
    for (int f = 0; f < NF; ++f) {
      int co = f * 16 + lq * 4;
      f32x4 bv = *(const f32x4*)&bias[co];
      s16x4 s;
      #pragma unroll
      for (int j = 0; j < 4; ++j) {
        float v = acc[f][j] + bv[j];
        if (LEAKY_) v = leaky(v);
        s[j] = (short)f2bf(v);
      }
      *(s16x4*)((unsigned short*)outp + ((size_t)(b * HP + y + 1) * WPAD + x + 1) * 64 + co) = s;
    }
  } else {
    int xs = x0 + wv * 16 + lq * 4;
    #pragma unroll
    for (int f = 0; f < NF; ++f) {
      int co = f * 16 + lr;
      float bv = bias[co];
      f32x4 o;
      #pragma unroll
      for (int j = 0; j < 4; ++j) {
        float v = acc[f][j] + bv;
        if (LEAKY_) v = leaky(v);
        int x = xs + j;
        v += bf2f(resid[((size_t)(b * HP + y + 1) * WPAD + x + 1) * 128 + co]);
        o[j] = v;
      }
      *(f32x4*)((float*)outp + ((size_t)(b * 64 + co) * HH + y) * WW + xs) = o;
    }
  }
}

// ---------------------------------------------------------------------------
// Deformable conv. Prev features sampled from concat_t channels [64,128).
// Two barriers per tap (R1-proven LDS discipline); tap k+1's gathers are
// issued into registers BEFORE tap k's GEMM so they stay in flight.
// ---------------------------------------------------------------------------
struct SampleRegs {
  bf16x8 v00[2], v01[2], v10[2], v11[2];
  float  c00[2], c01[2], c10[2], c11[2];
};

__device__ __forceinline__ void sample_issue(
    const unsigned short* __restrict__ cb,   // concat_t base for this b
    const unsigned short* __restrict__ off,  // offf base
    int b, int y, int x0, int pix, int g0, int k, SampleRegs& sr)
{
  int ky = k / 3, kx = k % 3;
  #pragma unroll
  for (int gi = 0; gi < 2; ++gi) {
    int g = g0 + gi * 4;
    const unsigned short* offp =
        off + ((size_t)(b * 144 + g * 18 + k * 2) * HH + y) * WW + x0 + pix;
    float dy = bf2f(offp[0]);
    float dx = bf2f(offp[HW_]);
    float py = (float)(y - 1 + ky) + dy;
    float px = (float)(x0 + pix - 1 + kx) + dx;
    float fy0 = floorf(py), fx0 = floorf(px);
    float wy1 = py - fy0, wx1 = px - fx0;
    float wy0 = 1.f - wy1, wx0 = 1.f - wx1;
    float fy1 = fy0 + 1.f, fx1 = fx0 + 1.f;
    bool vy0 = (fy0 >= 0.f) && (fy0 <= (float)(HH - 1));
    bool vy1 = (fy1 >= 0.f) && (fy1 <= (float)(HH - 1));
    bool vx0 = (fx0 >= 0.f) && (fx0 <= (float)(WW - 1));
    bool vx1 = (fx1 >= 0.f) && (fx1 <= (float)(WW - 1));
    int iy0 = (int)fminf(fmaxf(fy0, 0.f), (float)(HH - 1));
    int iy1 = (int)fminf(fmaxf(fy1, 0.f), (float)(HH - 1));
    int ix0 = (int)fminf(fmaxf(fx0, 0.f), (float)(WW - 1));
    int ix1 = (int)fminf(fmaxf(fx1, 0.f), (float)(WW - 1));
    sr.c00[gi] = wy0 * wx0 * ((vy0 && vx0) ? 1.f : 0.f);
    sr.c01[gi] = wy0 * wx1 * ((vy0 && vx1) ? 1.f : 0.f);
    sr.c10[gi] = wy1 * wx0 * ((vy1 && vx0) ? 1.f : 0.f);
    sr.c11[gi] = wy1 * wx1 * ((vy1 && vx1) ? 1.f : 0.f);
    // prev lives in concat_t channels [64,128): pixel (iy,ix) padded interior
    const unsigned short* xp = cb + 64 + g * 8;
    sr.v00[gi] = *(const bf16x8*)(xp + ((size_t)(iy0 + 1) * WPAD + ix0 + 1) * 128);
    sr.v01[gi] = *(const bf16x8*)(xp + ((size_t)(iy0 + 1) * WPAD + ix1 + 1) * 128);
    sr.v10[gi] = *(const bf16x8*)(xp + ((size_t)(iy1 + 1) * WPAD + ix0 + 1) * 128);
    sr.v11[gi] = *(const bf16x8*)(xp + ((size_t)(iy1 + 1) * WPAD + ix1 + 1) * 128);
  }
}

__device__ __forceinline__ void sample_combine(SampleRegs& sr, int pix, int g0,
                                               unsigned short (*patch)[72])
{
  #pragma unroll
  for (int gi = 0; gi < 2; ++gi) {
    int g = g0 + gi * 4;
    bf16x8 sv;
    #pragma unroll
    for (int j = 0; j < 8; ++j) {
      float s = bf2f((unsigned short)sr.v00[gi][j]) * sr.c00[gi]
              + bf2f((unsigned short)sr.v01[gi][j]) * sr.c01[gi]
              + bf2f((unsigned short)sr.v10[gi][j]) * sr.c10[gi]
              + bf2f((unsigned short)sr.v11[gi][j]) * sr.c11[gi];
      sv[j] = (short)f2bf(s);
    }
    *(bf16x8*)&patch[pix][g * 8] = sv;
  }
}

__global__ __launch_bounds__(256) void deform_mfma(
    const unsigned short* __restrict__ concatT, // [b][HP][WPAD][128]: reads ch64-127, writes ch0-63
    const unsigned short* __restrict__ off,     // [b][144][192][192] bf16
    const unsigned short* __restrict__ wB,      // [64][576] bf16
    const float* __restrict__ bias)
{
  __shared__ __align__(16) unsigned short patch[64][72];
  const int t  = threadIdx.x;
  const int l  = t & 63;
  const int wv = t >> 6;
  const int lr = l & 15, lq = l >> 4, lk = lq * 8;

  constexpr int NWG = 3 * 384;
  int lin = blockIdx.x + 3 * blockIdx.y;
  int swz = (lin & 7) * (NWG / 8) + (lin >> 3);
  int xq = swz % 3, yy = swz / 3;
  int y = yy % HH, b = yy / HH;
  int x0 = xq * 64;
  const int pix = l;
  const int g0  = wv;

  f32x4 acc[4];
  #pragma unroll
  for (int f = 0; f < 4; ++f) acc[f] = f32x4{0.f, 0.f, 0.f, 0.f};

  const unsigned short* cb = concatT + (size_t)b * HP * WPAD * 128;
  SampleRegs sr;

  // prologue: tap 0 sampled into patch
  sample_issue(cb, off, b, y, x0, pix, g0, 0, sr);
  sample_combine(sr, pix, g0, patch);

  for (int k = 0; k < 9; ++k) {
    __syncthreads();                          // patch for tap k visible
    if (k < 8) sample_issue(cb, off, b, y, x0, pix, g0, k + 1, sr);  // in flight during GEMM
    {
      const unsigned short* wbase = wB + (size_t)lr * 576 + k * 64 + lk;
      #pragma unroll
      for (int c = 0; c < 64; c += 32) {
        bf16x8 pf = *(const bf16x8*)&patch[wv * 16 + lr][c + lk];
        #pragma unroll
        for (int f = 0; f < 4; ++f) {
          bf16x8 wf = *(const bf16x8*)(wbase + c + (size_t)f * 16 * 576);
          acc[f] = __builtin_amdgcn_mfma_f32_16x16x32_bf16(wf, pf, acc[f], 0, 0, 0);
        }
      }
    }
    __syncthreads();                          // all GEMM reads of patch done
    if (k < 8) sample_combine(sr, pix, g0, patch);
  }

  // epilogue: NHWC bf16 into concat channels [0,64)
  int x = x0 + wv * 16 + lr;
  unsigned short* outc = (unsigned short*)concatT + (size_t)b * HP * WPAD * 128;
  #pragma unroll
  for (int f = 0; f < 4; ++f) {
    int co = f * 16 + lq * 4;
    f32x4 bv = *(const f32x4*)&bias[co];
    s16x4 s;
    #pragma unroll
    for (int j = 0; j < 4; ++j) s[j] = (short)f2bf(acc[f][j] + bv[j]);
    *(s16x4*)&outc[((size_t)(y + 1) * WPAD + x + 1) * 128 + co] = s;
  }
}

// ---------------------------------------------------------------------------
extern "C" void kernel_launch(void* const* d_in, const int* in_sizes, int n_in,
                              void* d_out, int out_size, void* d_ws, size_t ws_size,
                              hipStream_t stream)
{
  const float* prev  = (const float*)d_in[0];
  const float* offin = (const float*)d_in[1];
  const float* w_off = (const float*)d_in[2];
  const float* b_off = (const float*)d_in[3];
  const float* w_dcn = (const float*)d_in[4];
  const float* b_dcn = (const float*)d_in[5];
  const float* w_r1  = (const float*)d_in[6];
  const float* b_r1  = (const float*)d_in[7];
  const float* w_r2  = (const float*)d_in[8];
  const float* b_r2  = (const float*)d_in[9];
  float* out = (float*)d_out;

  char* p = (char*)d_ws;
  unsigned short* offs_t   = (unsigned short*)p; p += (size_t)B_ * HP * WPAD * 64 * 2;   //  9.93 MB
  unsigned short* concat_t = (unsigned short*)p; p += (size_t)B_ * HP * WPAD * 128 * 2;  // 19.87 MB
  unsigned short* r1_t     = (unsigned short*)p; p += (size_t)B_ * HP * WPAD * 64 * 2;   //  9.93 MB
  unsigned short* offf     = (unsigned short*)p; p += (size_t)B_ * 144 * HW_ * 2;        // 21.23 MB
  unsigned short* wOffB    = (unsigned short*)p; p += 144 * 576 * 2;
  unsigned short* wDcnB    = (unsigned short*)p; p += 64 * 576 * 2;
  unsigned short* wR1B     = (unsigned short*)p; p += 64 * 1152 * 2;
  unsigned short* wR2B     = (unsigned short*)p; p += 64 * 576 * 2;                      // total ~61.4 MB

  // Zero padded NHWC buffers (contiguous) so pad borders are 0.
  hipMemsetAsync(offs_t, 0, (size_t)B_ * HP * WPAD * (64 + 128 + 64) * 2, stream);

  wxform<<<900, 256, 0, stream>>>(w_off, w_dcn, w_r1, w_r2, wOffB, wDcnB, wR1B, wR2B);
  to_nhwc<64,  true ><<<dim3(12, 384), 256, 0, stream>>>(offin, offs_t, 0);
  to_nhwc<128, true ><<<dim3(12, 384), 256, 0, stream>>>(prev,  concat_t, 64);

  // K1: offset conv (64 -> 144), bf16 NCHW out.
  conv_mfma<64, 144, 9, false, 0><<<dim3(3, 384), 256, 0, stream>>>(
      offs_t, wOffB, b_off, nullptr, offf);

  // K2: deformable conv -> concat_t channels [0,64).
  deform_mfma<<<dim3(3, 384), 256, 0, stream>>>(concat_t, offf, wDcnB, b_dcn);

  // K3: r1 = leaky(conv(concat)) (128 -> 64), NHWC padded out.
  conv_mfma<128, 64, 4, true, 1><<<dim3(3, 384), 256, 0, stream>>>(
      concat_t, wR1B, b_r1, nullptr, r1_t);

  // K4: out = aligned + leaky(conv(r1)) (64 -> 64), f32 NCHW out.
  conv_mfma<64, 64, 4, true, 2><<<dim3(3, 384), 256, 0, stream>>>(
      r1_t, wR2B, b_r2, concat_t, out);
}

// Round 5
// 173.110 us; speedup vs baseline: 20.0608x; 2.0721x over previous
//
#include <hip/hip_runtime.h>
#include <hip/hip_bf16.h>
#include <cstdint>
#include <cstddef>

constexpr int B_ = 2;
constexpr int HH = 192, WW = 192, HW_ = HH * WW;
constexpr int HP = 194, WPAD = 200;   // padded dims

typedef short bf16x8 __attribute__((ext_vector_type(8)));
typedef short s16x4  __attribute__((ext_vector_type(4)));
typedef float f32x4  __attribute__((ext_vector_type(4)));

typedef __attribute__((address_space(1))) const void GLB;
typedef __attribute__((address_space(3))) void LDS;

__device__ __forceinline__ float bf2f(unsigned short h) {
  union { unsigned u; float f; } v; v.u = (unsigned)h << 16; return v.f;
}
__device__ __forceinline__ unsigned short f2bf(float f) {
  union { float f; unsigned u; } v; v.f = f;
  unsigned u = v.u;
  u += 0x7fffu + ((u >> 16) & 1u);
  return (unsigned short)(u >> 16);
}
__device__ __forceinline__ float leaky(float v) { return fmaxf(v, 0.1f * v); }

// ---------------------------------------------------------------------------
// NCHW f32 -> NHWC bf16 (optionally padded interior of [HP][WPAD]).
// ---------------------------------------------------------------------------
template<int DSTC, bool PAD>
__global__ __launch_bounds__(256) void to_nhwc(const float* __restrict__ src,
                                               unsigned short* __restrict__ dst,
                                               int coff)
{
  __shared__ float tile[16][65];
  int t = threadIdx.x;
  int xc = blockIdx.x * 16;
  int y = blockIdx.y % HH, b = blockIdx.y / HH;
  #pragma unroll
  for (int cp = 0; cp < 4; ++cp) {
    int c = cp * 16 + (t >> 4);
    tile[t & 15][c] = src[((size_t)(b * 64 + c) * HH + y) * WW + xc + (t & 15)];
  }
  __syncthreads();
  int x = t >> 4, c4 = (t & 15) * 4;
  s16x4 s;
  #pragma unroll
  for (int j = 0; j < 4; ++j) s[j] = (short)f2bf(tile[x][c4 + j]);
  size_t pbase = PAD
      ? ((size_t)(b * HP + y + 1) * WPAD + xc + x + 1) * DSTC + coff + c4
      : ((size_t)(b * HH + y) * WW + xc + x) * DSTC + coff + c4;
  *(s16x4*)&dst[pbase] = s;
}

// ---------------------------------------------------------------------------
// Weight transform: (O, CI, 3, 3) f32 -> tap-major LDS image [k][o][swz ci]
// bf16, with the XOR bank-swizzle pre-applied (pci = ((ci/8)^(o&7))*8+ci%8).
// ---------------------------------------------------------------------------
__global__ __launch_bounds__(256) void wxform(
    const float* __restrict__ w_off, const float* __restrict__ w_dcn,
    const float* __restrict__ w_r1,  const float* __restrict__ w_r2,
    unsigned short* __restrict__ wOffB, unsigned short* __restrict__ wDcnB,
    unsigned short* __restrict__ wR1B,  unsigned short* __restrict__ wR2B)
{
  int tid = blockIdx.x * 256 + threadIdx.x;   // 230400 total
  const float* src; unsigned short* dst; int CI, CO, idx;
  if (tid < 82944)            { src = w_off; dst = wOffB; CI = 64;  CO = 144; idx = tid; }
  else if (tid < 119808)      { src = w_dcn; dst = wDcnB; CI = 64;  CO = 64;  idx = tid - 82944; }
  else if (tid < 193536)      { src = w_r1;  dst = wR1B;  CI = 128; CO = 64;  idx = tid - 119808; }
  else                        { src = w_r2;  dst = wR2B;  CI = 64;  CO = 64;  idx = tid - 193536; }
  int ci = idx % CI;
  int k  = (idx / CI) % 9;
  int o  = idx / (CI * 9);
  int pci = ((((ci >> 3) ^ (o & 7))) << 3) | (ci & 7);
  dst[((size_t)k * CO + o) * CI + pci] = f2bf(src[((size_t)o * CI + ci) * 9 + k]);
}

// ---------------------------------------------------------------------------
// MFMA implicit-GEMM 3x3 conv. Pixels staged once in LDS; per-tap weights
// staged in LDS via global_load_lds (DBUF: double-buffered, 1 barrier/tap;
// else single-buffered, 2 barriers/tap). All operands read from LDS.
// OUTMODE 0: bf16 NCHW (K1) | 1: bf16 NHWC padded (K3) | 2: f32 NCHW + resid (K4)
// ---------------------------------------------------------------------------
template<int CIN, int COUT, int NF, bool LEAKY_, int OUTMODE, bool DBUF>
__global__ __launch_bounds__(256) void conv_mfma(
    const unsigned short* __restrict__ inT,   // [b][HP][WPAD][CIN] bf16
    const unsigned short* __restrict__ wS,    // [9][COUT][CIN] bf16, swizzled image
    const float* __restrict__ bias,
    const unsigned short* __restrict__ resid,
    void* __restrict__ outp)
{
  constexpr int CPP  = CIN / 8;          // 16B chunks per pixel
  constexpr int TPX  = 72;
  constexpr int NCH  = TPX * CPP;        // chunks per staged row
  constexpr int RPR  = NCH / 64;         // wave-regions per row
  constexpr int NREG = 3 * RPR;
  constexpr int WSZ  = COUT * CIN;       // weight elems per tap
  constexpr int WCH  = WSZ / 8;          // 16B chunks per tap
  __shared__ __align__(16) unsigned short tile[3 * TPX * CIN];
  __shared__ __align__(16) unsigned short wlds[(DBUF ? 2 : 1) * WSZ];

  const int t = threadIdx.x;
  const int l = t & 63, wv = t >> 6;
  const int lr = l & 15, lq = l >> 4, lk = lq * 8;

  // XCD-aware bijective swizzle (1152 % 8 == 0)
  constexpr int NWG = 3 * 384;
  int lin = blockIdx.x + 3 * blockIdx.y;
  int swz = (lin & 7) * (NWG / 8) + (lin >> 3);
  int xq = swz % 3, yy = swz / 3;
  int y = yy % HH, b = yy / HH;
  int x0 = xq * 64;

  // ---- stage 3 pixel rows (72 px each, swizzled) + weight tap 0
  {
    const unsigned short* base = inT + ((size_t)(b * HP + y) * WPAD + x0) * CIN;
    for (int r = wv; r < NREG; r += 4) {
      int row = r / RPR;
      int rr  = r % RPR;
      int d   = rr * 64 + l;
      int p   = d / CPP;
      int cj  = d % CPP;
      int sc  = p * CPP + (cj ^ (p & (CPP - 1)));
      const unsigned short* src = base + (size_t)row * WPAD * CIN + (size_t)sc * 8;
      unsigned short* dst = &tile[(size_t)(row * NCH + rr * 64) * 8];
      __builtin_amdgcn_global_load_lds((GLB*)src, (LDS*)dst, 16, 0, 0);
    }
  }
  {
    const unsigned short* srcb = wS;                 // tap 0
    for (int r = t; r < WCH; r += 256)
      __builtin_amdgcn_global_load_lds((GLB*)(srcb + (size_t)r * 8),
                                       (LDS*)(&wlds[(size_t)r * 8]), 16, 0, 0);
  }
  __syncthreads();

  f32x4 acc[NF];
  #pragma unroll
  for (int f = 0; f < NF; ++f) acc[f] = f32x4{0.f, 0.f, 0.f, 0.f};

  #pragma unroll
  for (int k = 0; k < 9; ++k) {
    const int ky = k / 3, kx = k % 3;
    if (DBUF && k < 8) {
      const unsigned short* srcb = wS + (size_t)(k + 1) * WSZ;
      unsigned short* db = &wlds[(size_t)((k + 1) & 1) * WSZ];
      for (int r = t; r < WCH; r += 256)
        __builtin_amdgcn_global_load_lds((GLB*)(srcb + (size_t)r * 8),
                                         (LDS*)(db + (size_t)r * 8), 16, 0, 0);
    }
    // ---- compute tap k
    {
      const unsigned short* wb = &wlds[DBUF ? (size_t)(k & 1) * WSZ : 0];
      const int px = wv * 16 + lr + kx;
      #pragma unroll
      for (int c = 0; c < CIN; c += 32) {
        int cj = (c + lk) >> 3;
        bf16x8 pf = *(const bf16x8*)
            &tile[(size_t)(ky * NCH + px * CPP + (cj ^ (px & (CPP - 1)))) * 8];
        #pragma unroll
        for (int f = 0; f < NF; ++f) {
          int co = f * 16 + lr;
          bf16x8 wf = *(const bf16x8*)&wb[(size_t)co * CIN + ((cj ^ (co & 7)) << 3)];
          if (OUTMODE == 0)
            acc[f] = __builtin_amdgcn_mfma_f32_16x16x32_bf16(pf, wf, acc[f], 0, 0, 0);
          else
            acc[f] = __builtin_amdgcn_mfma_f32_16x16x32_bf16(wf, pf, acc[f], 0, 0, 0);
        }
      }
    }
    if (DBUF) {
      __syncthreads();
    } else if (k < 8) {
      __syncthreads();                       // all reads of wlds done
      const unsigned short* srcb = wS + (size_t)(k + 1) * WSZ;
      for (int r = t; r < WCH; r += 256)
        __builtin_amdgcn_global_load_lds((GLB*)(srcb + (size_t)r * 8),
                                         (LDS*)(&wlds[(size_t)r * 8]), 16, 0, 0);
      __syncthreads();                       // staging complete
    }
  }

  if (OUTMODE == 0) {
    // C rows = px, cols = co (pf,wf orientation)
    int xs = x0 + wv * 16 + lq * 4;
    #pragma unroll
    for (int f = 0; f < NF; ++f) {
      int co = f * 16 + lr;
      float bv = bias[co];
      s16x4 s;
      #pragma unroll
      for (int j = 0; j < 4; ++j) {
        float v = acc[f][j] + bv;
        if (LEAKY_) v = leaky(v);
        s[j] = (short)f2bf(v);
      }
      *(s16x4*)((unsigned short*)outp + ((size_t)(b * COUT + co) * HH + y) * WW + xs) = s;
    }
  } else if (OUTMODE == 1) {
    // C rows = co, cols = px (wf,pf orientation): NHWC padded store
    int x = x0 + wv * 16 + lr;
    #pragma unroll
    for (int f = 0; f < NF; ++f) {
      int co = f * 16 + lq * 4;
      f32x4 bv = *(const f32x4*)&bias[co];
      s16x4 s;
      #pragma unroll
      for (int j = 0; j < 4; ++j) {
        float v = acc[f][j] + bv[j];
        if (LEAKY_) v = leaky(v);
        s[j] = (short)f2bf(v);
      }
      *(s16x4*)((unsigned short*)outp + ((size_t)(b * HP + y + 1) * WPAD + x + 1) * 64 + co) = s;
    }
  } else {
    // C rows = co, cols = px (wf,pf orientation): f32 NCHW + bf16 NHWC resid
    int x = x0 + wv * 16 + lr;
    const unsigned short* rbase = resid + ((size_t)(b * HP + y + 1) * WPAD + x + 1) * 128;
    float* ob = (float*)outp + (size_t)b * 64 * HW_ + (size_t)y * WW + x;
    #pragma unroll
    for (int f = 0; f < NF; ++f) {
      int cob = f * 16 + lq * 4;
      f32x4 bv = *(const f32x4*)&bias[cob];
      s16x4 rv = *(const s16x4*)&rbase[cob];
      #pragma unroll
      for (int j = 0; j < 4; ++j) {
        float v = acc[f][j] + bv[j];
        if (LEAKY_) v = leaky(v);
        v += bf2f((unsigned short)rv[j]);
        ob[(size_t)(cob + j) * HW_] = v;
      }
    }
  }
}

// ---------------------------------------------------------------------------
// Deformable conv. Prev features sampled from concat_t channels [64,128).
// Two barriers per tap; tap k+1's gathers issued before tap k's GEMM.
// Per-tap weights double-buffered in LDS (same swizzled image scheme).
// ---------------------------------------------------------------------------
struct SampleRegs {
  bf16x8 v00[2], v01[2], v10[2], v11[2];
  float  c00[2], c01[2], c10[2], c11[2];
};

__device__ __forceinline__ void sample_issue(
    const unsigned short* __restrict__ cb,   // concat_t base for this b
    const unsigned short* __restrict__ off,  // offf base
    int b, int y, int x0, int pix, int g0, int k, SampleRegs& sr)
{
  int ky = k / 3, kx = k % 3;
  #pragma unroll
  for (int gi = 0; gi < 2; ++gi) {
    int g = g0 + gi * 4;
    const unsigned short* offp =
        off + ((size_t)(b * 144 + g * 18 + k * 2) * HH + y) * WW + x0 + pix;
    float dy = bf2f(offp[0]);
    float dx = bf2f(offp[HW_]);
    float py = (float)(y - 1 + ky) + dy;
    float px = (float)(x0 + pix - 1 + kx) + dx;
    float fy0 = floorf(py), fx0 = floorf(px);
    float wy1 = py - fy0, wx1 = px - fx0;
    float wy0 = 1.f - wy1, wx0 = 1.f - wx1;
    float fy1 = fy0 + 1.f, fx1 = fx0 + 1.f;
    bool vy0 = (fy0 >= 0.f) && (fy0 <= (float)(HH - 1));
    bool vy1 = (fy1 >= 0.f) && (fy1 <= (float)(HH - 1));
    bool vx0 = (fx0 >= 0.f) && (fx0 <= (float)(WW - 1));
    bool vx1 = (fx1 >= 0.f) && (fx1 <= (float)(WW - 1));
    int iy0 = (int)fminf(fmaxf(fy0, 0.f), (float)(HH - 1));
    int iy1 = (int)fminf(fmaxf(fy1, 0.f), (float)(HH - 1));
    int ix0 = (int)fminf(fmaxf(fx0, 0.f), (float)(WW - 1));
    int ix1 = (int)fminf(fmaxf(fx1, 0.f), (float)(WW - 1));
    sr.c00[gi] = wy0 * wx0 * ((vy0 && vx0) ? 1.f : 0.f);
    sr.c01[gi] = wy0 * wx1 * ((vy0 && vx1) ? 1.f : 0.f);
    sr.c10[gi] = wy1 * wx0 * ((vy1 && vx0) ? 1.f : 0.f);
    sr.c11[gi] = wy1 * wx1 * ((vy1 && vx1) ? 1.f : 0.f);
    const unsigned short* xp = cb + 64 + g * 8;    // prev in concat ch[64,128)
    sr.v00[gi] = *(const bf16x8*)(xp + ((size_t)(iy0 + 1) * WPAD + ix0 + 1) * 128);
    sr.v01[gi] = *(const bf16x8*)(xp + ((size_t)(iy0 + 1) * WPAD + ix1 + 1) * 128);
    sr.v10[gi] = *(const bf16x8*)(xp + ((size_t)(iy1 + 1) * WPAD + ix0 + 1) * 128);
    sr.v11[gi] = *(const bf16x8*)(xp + ((size_t)(iy1 + 1) * WPAD + ix1 + 1) * 128);
  }
}

__device__ __forceinline__ void sample_combine(SampleRegs& sr, int pix, int g0,
                                               unsigned short (*patch)[72])
{
  #pragma unroll
  for (int gi = 0; gi < 2; ++gi) {
    int g = g0 + gi * 4;
    bf16x8 sv;
    #pragma unroll
    for (int j = 0; j < 8; ++j) {
      float s = bf2f((unsigned short)sr.v00[gi][j]) * sr.c00[gi]
              + bf2f((unsigned short)sr.v01[gi][j]) * sr.c01[gi]
              + bf2f((unsigned short)sr.v10[gi][j]) * sr.c10[gi]
              + bf2f((unsigned short)sr.v11[gi][j]) * sr.c11[gi];
      sv[j] = (short)f2bf(s);
    }
    *(bf16x8*)&patch[pix][g * 8] = sv;
  }
}

__global__ __launch_bounds__(256) void deform_mfma(
    const unsigned short* __restrict__ concatT, // [b][HP][WPAD][128]
    const unsigned short* __restrict__ off,     // [b][144][192][192] bf16
    const unsigned short* __restrict__ wS,      // [9][64][64] bf16 swizzled image
    const float* __restrict__ bias)
{
  __shared__ __align__(16) unsigned short patch[64][72];
  __shared__ __align__(16) unsigned short wlds[2][64 * 64];
  const int t  = threadIdx.x;
  const int l  = t & 63;
  const int wv = t >> 6;
  const int lr = l & 15, lq = l >> 4, lk = lq * 8;

  constexpr int NWG = 3 * 384;
  int lin = blockIdx.x + 3 * blockIdx.y;
  int swz = (lin & 7) * (NWG / 8) + (lin >> 3);
  int xq = swz % 3, yy = swz / 3;
  int y = yy % HH, b = yy / HH;
  int x0 = xq * 64;
  const int pix = l;
  const int g0  = wv;

  f32x4 acc[4];
  #pragma unroll
  for (int f = 0; f < 4; ++f) acc[f] = f32x4{0.f, 0.f, 0.f, 0.f};

  const unsigned short* cb = concatT + (size_t)b * HP * WPAD * 128;
  SampleRegs sr;

  // prologue: tap 0 sampled into patch; weight tap 0 staged
  sample_issue(cb, off, b, y, x0, pix, g0, 0, sr);
  {
    for (int r = t; r < 512; r += 256)
      __builtin_amdgcn_global_load_lds((GLB*)(wS + (size_t)r * 8),
                                       (LDS*)(&wlds[0][(size_t)r * 8]), 16, 0, 0);
  }
  sample_combine(sr, pix, g0, patch);

  for (int k = 0; k < 9; ++k) {
    __syncthreads();                          // patch k + wlds[k&1] ready
    if (k < 8) {
      sample_issue(cb, off, b, y, x0, pix, g0, k + 1, sr);   // in flight
      const unsigned short* srcb = wS + (size_t)(k + 1) * 4096;
      unsigned short* db = &wlds[(k + 1) & 1][0];
      for (int r = t; r < 512; r += 256)
        __builtin_amdgcn_global_load_lds((GLB*)(srcb + (size_t)r * 8),
                                         (LDS*)(db + (size_t)r * 8), 16, 0, 0);
    }
    {
      const unsigned short* wb = &wlds[k & 1][0];
      #pragma unroll
      for (int c = 0; c < 64; c += 32) {
        int cj = (c + lk) >> 3;
        bf16x8 pf = *(const bf16x8*)&patch[wv * 16 + lr][c + lk];
        #pragma unroll
        for (int f = 0; f < 4; ++f) {
          int co = f * 16 + lr;
          bf16x8 wf = *(const bf16x8*)&wb[(size_t)co * 64 + ((cj ^ (co & 7)) << 3)];
          acc[f] = __builtin_amdgcn_mfma_f32_16x16x32_bf16(wf, pf, acc[f], 0, 0, 0);
        }
      }
    }
    __syncthreads();                          // all GEMM reads of patch done
    if (k < 8) sample_combine(sr, pix, g0, patch);
  }

  // epilogue: NHWC bf16 into concat channels [0,64)
  int x = x0 + wv * 16 + lr;
  unsigned short* outc = (unsigned short*)concatT + (size_t)b * HP * WPAD * 128;
  #pragma unroll
  for (int f = 0; f < 4; ++f) {
    int co = f * 16 + lq * 4;
    f32x4 bv = *(const f32x4*)&bias[co];
    s16x4 s;
    #pragma unroll
    for (int j = 0; j < 4; ++j) s[j] = (short)f2bf(acc[f][j] + bv[j]);
    *(s16x4*)&outc[((size_t)(y + 1) * WPAD + x + 1) * 128 + co] = s;
  }
}

// ---------------------------------------------------------------------------
extern "C" void kernel_launch(void* const* d_in, const int* in_sizes, int n_in,
                              void* d_out, int out_size, void* d_ws, size_t ws_size,
                              hipStream_t stream)
{
  const float* prev  = (const float*)d_in[0];
  const float* offin = (const float*)d_in[1];
  const float* w_off = (const float*)d_in[2];
  const float* b_off = (const float*)d_in[3];
  const float* w_dcn = (const float*)d_in[4];
  const float* b_dcn = (const float*)d_in[5];
  const float* w_r1  = (const float*)d_in[6];
  const float* b_r1  = (const float*)d_in[7];
  const float* w_r2  = (const float*)d_in[8];
  const float* b_r2  = (const float*)d_in[9];
  float* out = (float*)d_out;

  char* p = (char*)d_ws;
  unsigned short* offs_t   = (unsigned short*)p; p += (size_t)B_ * HP * WPAD * 64 * 2;   //  9.93 MB
  unsigned short* concat_t = (unsigned short*)p; p += (size_t)B_ * HP * WPAD * 128 * 2;  // 19.87 MB
  unsigned short* r1_t     = (unsigned short*)p; p += (size_t)B_ * HP * WPAD * 64 * 2;   //  9.93 MB
  unsigned short* offf     = (unsigned short*)p; p += (size_t)B_ * 144 * HW_ * 2;        // 21.23 MB
  unsigned short* wOffB    = (unsigned short*)p; p += 144 * 576 * 2;
  unsigned short* wDcnB    = (unsigned short*)p; p += 64 * 576 * 2;
  unsigned short* wR1B     = (unsigned short*)p; p += 64 * 1152 * 2;
  unsigned short* wR2B     = (unsigned short*)p; p += 64 * 576 * 2;                      // total ~61.4 MB

  // Zero padded NHWC buffers (contiguous) so pad borders are 0.
  hipMemsetAsync(offs_t, 0, (size_t)B_ * HP * WPAD * (64 + 128 + 64) * 2, stream);

  wxform<<<900, 256, 0, stream>>>(w_off, w_dcn, w_r1, w_r2, wOffB, wDcnB, wR1B, wR2B);
  to_nhwc<64,  true ><<<dim3(12, 384), 256, 0, stream>>>(offin, offs_t, 0);
  to_nhwc<128, true ><<<dim3(12, 384), 256, 0, stream>>>(prev,  concat_t, 64);

  // K1: offset conv (64 -> 144), bf16 NCHW out. LDS 27.6+36.9=64.5 KB (DBUF)
  conv_mfma<64, 144, 9, false, 0, true><<<dim3(3, 384), 256, 0, stream>>>(
      offs_t, wOffB, b_off, nullptr, offf);

  // K2: deformable conv -> concat_t channels [0,64). LDS 9.2+16.4=25.6 KB
  deform_mfma<<<dim3(3, 384), 256, 0, stream>>>(concat_t, offf, wDcnB, b_dcn);

  // K3: r1 = leaky(conv(concat)) (128 -> 64). LDS 55.3+16.4=71.7 KB (single buf)
  conv_mfma<128, 64, 4, true, 1, false><<<dim3(3, 384), 256, 0, stream>>>(
      concat_t, wR1B, b_r1, nullptr, r1_t);

  // K4: out = aligned + leaky(conv(r1)) (64 -> 64). LDS 27.6+18.4=46 KB (DBUF)
  conv_mfma<64, 64, 4, true, 2, true><<<dim3(3, 384), 256, 0, stream>>>(
      r1_t, wR2B, b_r2, concat_t, out);
}